// Round 9
// baseline (65.707 us; speedup 1.0000x reference)
//
#include <hip/hip_runtime.h>
#include <math.h>

// Problem constants (fixed by the reference)
#define NB   8        // batch
#define LQN  4096     // queries
#define DM   256      // d_model
#define MH   8        // heads
#define PP   4        // points
#define HH   64       // H
#define WW   64       // W
#define LG   128      // padded logits row stride (96 real + 32 pad/garbage)
#define PW   67       // padded image width/height (x,y in -1..65)
#define PPIX (PW*PW)  // 4489 padded pixels per batch

typedef __bf16 bf16x8 __attribute__((ext_vector_type(8)));
typedef float  f32x4  __attribute__((ext_vector_type(4)));
typedef unsigned short us8 __attribute__((ext_vector_type(8)));
typedef unsigned short us4 __attribute__((ext_vector_type(4)));

__device__ __forceinline__ unsigned short f2bf(float f) {   // RNE fp32 -> bf16 bits
    unsigned u = __float_as_uint(f);
    u += 0x7FFFu + ((u >> 16) & 1u);
    return (unsigned short)(u >> 16);
}
__device__ __forceinline__ float bf2f(unsigned short b) {
    return __uint_as_float((unsigned)b << 16);
}

__device__ __forceinline__ void gl2lds16(const void* g, unsigned short* l) {
    __builtin_amdgcn_global_load_lds(
        (const __attribute__((address_space(1))) void*)g,
        (__attribute__((address_space(3))) void*)l,
        16, 0, 0);
}

// Convert a swizzled fp32 LDS row-pair (two 16B units) to a bf16x8 fragment.
// LDS layout: [128 rows][8 units of 16B], unit for k-quad q of row r sits at
// r*8 + (q ^ (r&7)).  (write side: linear DMA dest, XOR-swizzled global src)
__device__ __forceinline__ bf16x8 cvt_frag(const unsigned short* s, int row, int kq) {
    const int u0 = row * 8 + ((kq * 2) ^ (row & 7));
    const int u1 = u0 ^ 1;
    const f32x4 a0 = *(const f32x4*)&s[u0 * 8];
    const f32x4 a1 = *(const f32x4*)&s[u1 * 8];
    bf16x8 v;
    v[0] = (__bf16)a0[0]; v[1] = (__bf16)a0[1];
    v[2] = (__bf16)a0[2]; v[3] = (__bf16)a0[3];
    v[4] = (__bf16)a1[0]; v[5] = (__bf16)a1[1];
    v[6] = (__bf16)a1[2]; v[7] = (__bf16)a1[3];
    return v;
}

// ---------------------------------------------------------------------------
// Dual GEMM, both operands fp32 staged via global_load_lds (XOR-swizzled
// source), bf16-converted on the read side. 2-deep counted-vmcnt pipeline.
//   blocks [0,512):   value  = input @ Wv^T + bv  -> scatter to padded image
//   blocks [512,768): logits = query @ [Woff;Wa]^T + bias -> [32768][128] bf16
//                     (output cols 96-127 are don't-care garbage, never read)
// Value blocks use XCD-paired mapping: row-tile partners are blk and blk+8
// (same blk%8 -> same XCD L2) so the A-tile is HBM-fetched once.
// Epilogue additionally zeroes the padded-image border (no prep kernel).
// ---------------------------------------------------------------------------
__global__ __launch_bounds__(256, 2)
void dual_gemm(const float* __restrict__ Ain, const float* __restrict__ Aq,
               const float* __restrict__ Wv,  const float* __restrict__ Woff,
               const float* __restrict__ Wa,  const float* __restrict__ bv,
               const float* __restrict__ boff, const float* __restrict__ ba,
               unsigned short* __restrict__ valueP,
               unsigned short* __restrict__ logitsB) {
    constexpr int K = 256, NK = 8;
    __shared__ unsigned short sA[2][8192];   // [128][32] fp32, swizzled cols
    __shared__ unsigned short sB[2][8192];

    const int t   = threadIdx.x;
    const int blk = blockIdx.x;
    const bool isVal = (blk < 512);

    const float* A;
    int brow, bcol;
    if (isVal) {           // XCD-paired: partners blk, blk+8 share brow
        const int g = blk >> 4, w = blk & 15;
        brow = (g * 8 + (w & 7)) * 128;
        bcol = ((w >> 3) & 1) * 128;
        A = Ain;
    } else {
        brow = (blk - 512) * 128; bcol = 0; A = Aq;
    }

    // staging map: thread t -> row i*32 + (t>>3), swizzled col-quad
    const int srow = t >> 3;                      // 0..31
    const int scq  = (t & 7) ^ (srow & 7);        // swizzled col4
    const float* aG = A + (size_t)(brow + srow) * K + scq * 4;
    const size_t aIss = (size_t)32 * K;

    const float *bS0, *bS1, *bS2, *bS3;           // per-issue B sources
    if (isVal) {
        bS0 = Wv + (size_t)(bcol +  0 + srow) * K + scq * 4;
        bS1 = Wv + (size_t)(bcol + 32 + srow) * K + scq * 4;
        bS2 = Wv + (size_t)(bcol + 64 + srow) * K + scq * 4;
        bS3 = Wv + (size_t)(bcol + 96 + srow) * K + scq * 4;
    } else {   // rows 0-63 Woff, 64-95 Wa, 96-127 dummy (Woff, output unused)
        bS0 = Woff + (size_t)(srow)      * K + scq * 4;
        bS1 = Woff + (size_t)(32 + srow) * K + scq * 4;
        bS2 = Wa   + (size_t)(srow)      * K + scq * 4;
        bS3 = Woff + (size_t)(srow)      * K + scq * 4;
    }

    const int l   = t & 63;
    const int wid = t >> 6;
    const int wr  = wid >> 1, wc = wid & 1;
    const int fr  = l & 15,   kq = l >> 4;

    f32x4 acc[4][4] = {};

#define STAGE(buf, ks_) { const int k0_ = (ks_) * 32;                    \
       gl2lds16(aG + k0_,            &sA[buf][t * 8]);                   \
       gl2lds16(aG + k0_ + aIss,     &sA[buf][2048 + t * 8]);            \
       gl2lds16(aG + k0_ + 2 * aIss, &sA[buf][4096 + t * 8]);            \
       gl2lds16(aG + k0_ + 3 * aIss, &sA[buf][6144 + t * 8]);            \
       gl2lds16(bS0 + k0_,           &sB[buf][t * 8]);                   \
       gl2lds16(bS1 + k0_,           &sB[buf][2048 + t * 8]);            \
       gl2lds16(bS2 + k0_,           &sB[buf][4096 + t * 8]);            \
       gl2lds16(bS3 + k0_,           &sB[buf][6144 + t * 8]); }

    STAGE(0, 0);                     //  8 outstanding
    STAGE(1, 1);                     // 16 outstanding

    for (int ks = 0; ks < NK; ++ks) {
        const int cur = ks & 1;
        // wait for the OLDEST stage only; the newest 8 stay in flight
        if (ks < NK - 1) asm volatile("s_waitcnt vmcnt(8)" ::: "memory");
        else             asm volatile("s_waitcnt vmcnt(0)" ::: "memory");
        __builtin_amdgcn_s_barrier();
        __builtin_amdgcn_sched_barrier(0);

        bf16x8 af[4], bf_[4];
#pragma unroll
        for (int m = 0; m < 4; ++m)
            af[m]  = cvt_frag(sA[cur], wr * 64 + m * 16 + fr, kq);
#pragma unroll
        for (int n = 0; n < 4; ++n)
            bf_[n] = cvt_frag(sB[cur], wc * 64 + n * 16 + fr, kq);

#pragma unroll
        for (int m = 0; m < 4; ++m)
#pragma unroll
            for (int n = 0; n < 4; ++n)   // swapped operands: C[m16+fr][n16+kq4+j]
                acc[m][n] = __builtin_amdgcn_mfma_f32_16x16x32_bf16(
                    bf_[n], af[m], acc[m][n], 0, 0, 0);

        __builtin_amdgcn_sched_barrier(0);
        __builtin_amdgcn_s_barrier();    // all waves done reading buf cur
        if (ks + 2 < NK) STAGE(cur, ks + 2);
    }
#undef STAGE

    // epilogue: thread owns row (..+fr), 4 consecutive cols (..+kq*4+j)
#pragma unroll
    for (int m = 0; m < 4; ++m) {
        const int row = brow + wr * 64 + m * 16 + fr;
        size_t rbase;
        if (isVal) {
            const int nb_ = row >> 12;
            const int pix = row & 4095;
            const int y   = pix >> 6, x = pix & 63;
            rbase = ((size_t)nb_ * PPIX + (size_t)(y + 1) * PW + (x + 1)) * DM;
        } else {
            rbase = (size_t)row * LG;
        }
#pragma unroll
        for (int n = 0; n < 4; ++n) {
            const int colq = bcol + wc * 64 + n * 16 + kq * 4;
            float4 b4;
            if (isVal)            b4 = *(const float4*)&bv[colq];
            else if (colq < 64)   b4 = *(const float4*)&boff[colq];
            else if (colq < 96)   b4 = *(const float4*)&ba[colq - 64];
            else                  b4 = make_float4(0.f, 0.f, 0.f, 0.f);
            us4 o;
            o[0] = f2bf(acc[m][n][0] + b4.x);
            o[1] = f2bf(acc[m][n][1] + b4.y);
            o[2] = f2bf(acc[m][n][2] + b4.z);
            o[3] = f2bf(acc[m][n][3] + b4.w);
            *(us4*)&(isVal ? valueP : logitsB)[rbase + colq] = o;
        }
    }

    // border zeroing (393 border pixels/batch x 64 ushort4), all blocks help
    const int gtid = blk * 256 + t;
    for (int i = gtid; i < 201216; i += 196608) {
        const int c4  = i & 63;
        const int pix = i >> 6;
        const int n   = pix / 393;
        const int r   = pix - n * 393;
        int x, y;
        if (r < 201) {
            const int q = r / 67;
            y = (q == 0) ? 0 : (q == 1 ? 65 : 66);
            x = r - q * 67;
        } else {
            const int q = r - 201;
            y = 1 + q / 3;
            const int s = q - (q / 3) * 3;
            x = (s == 0) ? 0 : (s == 1 ? 65 : 66);
        }
        const size_t addr = ((size_t)n * PPIX + (size_t)y * PW + x) * DM + c4 * 4;
        *(ushort4*)&valueP[addr] = make_ushort4(0, 0, 0, 0);
    }
}

// ---------------------------------------------------------------------------
// out = sampledH @ Wo^T + bo (fp32 out). A bf16 via linear gl2lds; B = Wo
// fp32 staged swizzled + read-side cvt. 2-deep counted pipeline, XCD-paired
// row-tile mapping (same as dual_gemm value part).
// ---------------------------------------------------------------------------
__global__ __launch_bounds__(256, 2)
void gemm_out(const unsigned short* __restrict__ A,
              const float* __restrict__ Wo,
              const float* __restrict__ bo, float* __restrict__ C) {
    constexpr int K = 256, N = DM, NK = 8;
    __shared__ unsigned short sA[2][4096];   // [128][32] bf16 linear
    __shared__ unsigned short sB[2][8192];   // [128][32] fp32 swizzled

    const int t   = threadIdx.x;
    const int blk = blockIdx.x;              // 0..511
    const int g = blk >> 4, w = blk & 15;    // XCD-paired mapping
    const int brow = (g * 8 + (w & 7)) * 128;
    const int bcol = ((w >> 3) & 1) * 128;

    const unsigned short* aG = A + (size_t)(brow + (t >> 2)) * K + (t & 3) * 8;
    const size_t ars64 = (size_t)64 * K;

    const int srow = t >> 3;
    const int scq  = (t & 7) ^ (srow & 7);
    const float* bS0 = Wo + (size_t)(bcol +  0 + srow) * K + scq * 4;
    const float* bS1 = Wo + (size_t)(bcol + 32 + srow) * K + scq * 4;
    const float* bS2 = Wo + (size_t)(bcol + 64 + srow) * K + scq * 4;
    const float* bS3 = Wo + (size_t)(bcol + 96 + srow) * K + scq * 4;

    const int l   = t & 63;
    const int wid = t >> 6;
    const int wr  = wid >> 1, wc = wid & 1;
    const int fr  = l & 15,   kq = l >> 4;

    f32x4 acc[4][4] = {};

#define STAGEO(buf, ks_) { const int k0_ = (ks_) * 32;                   \
       gl2lds16(aG + k0_,         &sA[buf][t * 8]);                      \
       gl2lds16(aG + k0_ + ars64, &sA[buf][2048 + t * 8]);               \
       gl2lds16(bS0 + k0_,        &sB[buf][t * 8]);                      \
       gl2lds16(bS1 + k0_,        &sB[buf][2048 + t * 8]);               \
       gl2lds16(bS2 + k0_,        &sB[buf][4096 + t * 8]);               \
       gl2lds16(bS3 + k0_,        &sB[buf][6144 + t * 8]); }

    STAGEO(0, 0);                    //  6 outstanding
    STAGEO(1, 1);                    // 12 outstanding

    for (int ks = 0; ks < NK; ++ks) {
        const int cur = ks & 1;
        if (ks < NK - 1) asm volatile("s_waitcnt vmcnt(6)" ::: "memory");
        else             asm volatile("s_waitcnt vmcnt(0)" ::: "memory");
        __builtin_amdgcn_s_barrier();
        __builtin_amdgcn_sched_barrier(0);

        bf16x8 af[4], bfr[4];
#pragma unroll
        for (int m = 0; m < 4; ++m)
            af[m]  = *(const bf16x8*)&sA[cur][(wr * 64 + m * 16 + fr) * 32 + kq * 8];
#pragma unroll
        for (int n = 0; n < 4; ++n)
            bfr[n] = cvt_frag(sB[cur], wc * 64 + n * 16 + fr, kq);

#pragma unroll
        for (int m = 0; m < 4; ++m)
#pragma unroll
            for (int n = 0; n < 4; ++n)   // swapped: C[m16+fr][n16+kq4+j]
                acc[m][n] = __builtin_amdgcn_mfma_f32_16x16x32_bf16(
                    bfr[n], af[m], acc[m][n], 0, 0, 0);

        __builtin_amdgcn_sched_barrier(0);
        __builtin_amdgcn_s_barrier();
        if (ks + 2 < NK) STAGEO(cur, ks + 2);
    }
#undef STAGEO

#pragma unroll
    for (int m = 0; m < 4; ++m) {
        const int row = brow + wr * 64 + m * 16 + fr;
#pragma unroll
        for (int n = 0; n < 4; ++n) {
            const int colq = bcol + wc * 64 + n * 16 + kq * 4;
            const float4 bs = *(const float4*)&bo[colq];
            float4 o;
            o.x = acc[m][n][0] + bs.x; o.y = acc[m][n][1] + bs.y;
            o.z = acc[m][n][2] + bs.z; o.w = acc[m][n][3] + bs.w;
            *(float4*)&C[(size_t)row * N + colq] = o;
        }
    }
}

// ---------------------------------------------------------------------------
// Fused softmax + bilinear sampling — one wave per query.
// half = lane>>5 owns y-corner; c8 = lane&31 owns channels [c8*8,+8).
// Two 16B gathers per point per half; halves combined via shfl_xor(32).
// Branch-free via zero-padded image + clamp. XCD-swizzled (batch k -> XCD k).
// ---------------------------------------------------------------------------
__global__ __launch_bounds__(256)
void sample_kernel(const float* __restrict__ refp,
                   const unsigned short* __restrict__ valueP,
                   const unsigned short* __restrict__ logitsB,
                   unsigned short* __restrict__ sampledH) {
    const int vb   = (blockIdx.x & 7) * 1024 + (blockIdx.x >> 3);
    const int wid  = threadIdx.x >> 6;
    const int b    = vb * 4 + wid;
    const int n    = b >> 12;
    const int lane = threadIdx.x & 63;

    const int tp  = lane & 31;
    const int pm  = tp >> 2, ppt = tp & 3;
    const unsigned short* lg = logitsB + (size_t)b * LG;

    const float rx = refp[(size_t)b * 2 + 0];
    const float ry = refp[(size_t)b * 2 + 1];
    const float ox = bf2f(lg[pm * 8 + ppt * 2 + 0]);
    const float oy = bf2f(lg[pm * 8 + ppt * 2 + 1]);
    const float la = bf2f(lg[64 + tp]);

    const float x = fminf(fmaxf(fmaf(rx, (float)WW, ox) - 0.5f, -1.0f), 64.0f);
    const float y = fminf(fmaxf(fmaf(ry, (float)HH, oy) - 0.5f, -1.0f), 64.0f);

    float mx = fmaxf(la, __shfl_xor(la, 1));
    mx = fmaxf(mx, __shfl_xor(mx, 2));
    const float e = __expf(la - mx);
    float den = e + __shfl_xor(e, 1);
    den += __shfl_xor(den, 2);
    const float w = e / den;

    const int half = lane >> 5;
    const int c8   = lane & 31;
    const int mh   = c8 >> 2;
    const unsigned short* vbase = valueP + (size_t)n * (PPIX * DM) + c8 * 8;

    float accv[8] = {};
#pragma unroll
    for (int p = 0; p < PP; ++p) {
        const int   sl = mh * PP + p;
        const float xp = __shfl(x, sl);
        const float yp = __shfl(y, sl);
        const float wp = __shfl(w, sl);

        const float x0f = floorf(xp), y0f = floorf(yp);
        const int   x0 = (int)x0f,   y0 = (int)y0f;
        const float wx1 = xp - x0f,  wy1 = yp - y0f;
        const float wy  = half ? wy1 : (1.f - wy1);
        const float wA  = wp * wy * (1.f - wx1);
        const float wB  = wp * wy * wx1;

        const unsigned short* p0 =
            vbase + (size_t)((y0 + 1 + half) * PW + (x0 + 1)) * DM;
        const us8 gA = *(const us8*)(p0);
        const us8 gB = *(const us8*)(p0 + DM);
#pragma unroll
        for (int j = 0; j < 8; ++j) {
            accv[j] = fmaf(wA, bf2f(gA[j]), accv[j]);
            accv[j] = fmaf(wB, bf2f(gB[j]), accv[j]);
        }
    }

#pragma unroll
    for (int j = 0; j < 8; ++j)
        accv[j] += __shfl_xor(accv[j], 32);

    if (half == 0) {
        us8 o;
#pragma unroll
        for (int j = 0; j < 8; ++j) o[j] = f2bf(accv[j]);
        *(us8*)&sampledH[(size_t)b * DM + c8 * 8] = o;
    }
}

// ---------------------------------------------------------------------------
extern "C" void kernel_launch(void* const* d_in, const int* in_sizes, int n_in,
                              void* d_out, int out_size, void* d_ws, size_t ws_size,
                              hipStream_t stream) {
    const float* query  = (const float*)d_in[0];   // [8,4096,256]
    const float* refp   = (const float*)d_in[1];   // [8,4096,2]
    const float* inputf = (const float*)d_in[2];   // [8,4096,256]
    const float* Wv   = (const float*)d_in[5];     // [256,256]
    const float* bv   = (const float*)d_in[6];     // [256]
    const float* Woff = (const float*)d_in[7];     // [64,256]
    const float* boff = (const float*)d_in[8];     // [64]
    const float* Wa   = (const float*)d_in[9];     // [32,256]
    const float* ba   = (const float*)d_in[10];    // [32]
    const float* Wo   = (const float*)d_in[11];    // [256,256]
    const float* bo   = (const float*)d_in[12];    // [256]
    float* out = (float*)d_out;

    const int Mrows = NB * LQN;  // 32768

    // workspace layout (ushort units)
    unsigned short* sampledH = (unsigned short*)d_ws;              //  8,388,608
    unsigned short* valueP   = sampledH + (size_t)Mrows * DM;      //  9,193,472
    unsigned short* logitsB  = valueP   + (size_t)NB * PPIX * DM;  //  4,194,304

    // 1. dual GEMM (read-side fp32->bf16 cvt, counted vmcnt, XCD-paired)
    dual_gemm<<<768, 256, 0, stream>>>(inputf, query, Wv, Woff, Wa,
                                       bv, boff, ba, valueP, logitsB);

    // 2. softmax + bilinear sampling -> sampledH (bf16)
    sample_kernel<<<Mrows / 4, 256, 0, stream>>>(refp, valueP, logitsB, sampledH);

    // 3. out = sampled @ Wo^T + bo (fp32 out)
    gemm_out<<<512, 256, 0, stream>>>(sampledH, Wo, bo, out);
}

// Round 10
// 62.390 us; speedup vs baseline: 1.0532x; 1.0532x over previous
//
#include <hip/hip_runtime.h>
#include <math.h>

// Problem constants (fixed by the reference)
#define NB   8        // batch
#define LQN  4096     // queries
#define DM   256      // d_model
#define MH   8        // heads
#define PP   4        // points
#define HH   64       // H
#define WW   64       // W
#define LG   128      // padded logits row stride (96 real + 32 pad)
#define PW   67       // padded image width/height (x,y in -1..65)
#define PPIX (PW*PW)  // 4489 padded pixels per batch

typedef __bf16 bf16x8 __attribute__((ext_vector_type(8)));
typedef float  f32x4  __attribute__((ext_vector_type(4)));
typedef unsigned short us8 __attribute__((ext_vector_type(8)));
typedef unsigned short us4 __attribute__((ext_vector_type(4)));

__device__ __forceinline__ unsigned short f2bf(float f) {   // RNE fp32 -> bf16 bits
    unsigned u = __float_as_uint(f);
    u += 0x7FFFu + ((u >> 16) & 1u);
    return (unsigned short)(u >> 16);
}
__device__ __forceinline__ float bf2f(unsigned short b) {
    return __uint_as_float((unsigned)b << 16);
}

__device__ __forceinline__ void gl2lds16(const void* g, unsigned short* l) {
    __builtin_amdgcn_global_load_lds(
        (const __attribute__((address_space(1))) void*)g,
        (__attribute__((address_space(3))) void*)l,
        16, 0, 0);
}

// Convert a swizzled fp32 LDS row-pair (two 16B units) to a bf16x8 fragment.
// LDS layout: [rows][8 units of 16B], unit for k-quad q of row r at
// r*8 + (q ^ (r&7)); write side is linear DMA dest + XOR-swizzled global src.
__device__ __forceinline__ bf16x8 cvt_frag(const unsigned short* s, int row, int kq) {
    const int u0 = row * 8 + ((kq * 2) ^ (row & 7));
    const int u1 = u0 ^ 1;
    const f32x4 a0 = *(const f32x4*)&s[u0 * 8];
    const f32x4 a1 = *(const f32x4*)&s[u1 * 8];
    bf16x8 v;
    v[0] = (__bf16)a0[0]; v[1] = (__bf16)a0[1];
    v[2] = (__bf16)a0[2]; v[3] = (__bf16)a0[3];
    v[4] = (__bf16)a1[0]; v[5] = (__bf16)a1[1];
    v[6] = (__bf16)a1[2]; v[7] = (__bf16)a1[3];
    return v;
}

// ---------------------------------------------------------------------------
// Prep: weight bf16 conversion (Wvh, Woh [256][256]; Wcath [128][256] rows
// 96-127 zero; bcat fp32[128]) + zero the padded-image border.
// ---------------------------------------------------------------------------
__global__ __launch_bounds__(256)
void prep_kernel(const float* __restrict__ Wv, const float* __restrict__ Wo,
                 const float* __restrict__ Woff, const float* __restrict__ Wa,
                 const float* __restrict__ boff, const float* __restrict__ ba,
                 unsigned short* __restrict__ Wvh, unsigned short* __restrict__ Woh,
                 unsigned short* __restrict__ Wcath, float* __restrict__ bcat,
                 unsigned short* __restrict__ valueP) {
    const int i = blockIdx.x * 256 + threadIdx.x;
    if (i < 65536) {
        Wvh[i] = f2bf(Wv[i]);
    } else if (i < 131072) {
        const int j = i - 65536;
        Woh[j] = f2bf(Wo[j]);
    } else if (i < 163840) {
        const int j = i - 131072, n = j >> 8, k = j & 255;
        const float v = (n < 64) ? Woff[n * 256 + k]
                                 : ((n < 96) ? Wa[(n - 64) * 256 + k] : 0.f);
        Wcath[j] = f2bf(v);
    } else if (i < 163968) {
        const int n = i - 163840;
        bcat[n] = (n < 64) ? boff[n] : ((n < 96) ? ba[n - 64] : 0.f);
    } else if (i < 163968 + 201216) {
        // border pixels: 393 per batch (rows y=0,65,66 full; x in {0,65,66})
        const int j   = i - 163968;
        const int c4  = j & 63;
        const int pix = j >> 6;
        const int n   = pix / 393;
        const int r   = pix - n * 393;
        int x, y;
        if (r < 201) {
            const int q = r / 67;
            y = (q == 0) ? 0 : (q == 1 ? 65 : 66);
            x = r - q * 67;
        } else {
            const int q = r - 201;
            y = 1 + q / 3;
            const int s = q - (q / 3) * 3;
            x = (s == 0) ? 0 : (s == 1 ? 65 : 66);
        }
        const size_t addr = ((size_t)n * PPIX + (size_t)y * PW + x) * DM + c4 * 4;
        *(ushort4*)&valueP[addr] = make_ushort4(0, 0, 0, 0);
    }
}

// ---------------------------------------------------------------------------
// Dual GEMM, BM=64 / BN=128, high-occupancy (32 KB LDS -> 4-5 blocks/CU).
//   blocks [0,1024):    value  = input @ Wvh^T + bv  -> scatter to padded img
//   blocks [1024,1536): logits = query @ Wcath^T + bcat -> [32768][128] bf16
// A fp32 via gl2lds (XOR-swizzled source) + read-side cvt; B bf16 linear.
// 2-deep counted-vmcnt pipeline (4 loads/stage, vmcnt(4)).
// Value blocks XCD-paired: partners blk, blk+8 share the A row-tile.
// ---------------------------------------------------------------------------
__global__ __launch_bounds__(256, 4)
void dual_gemm(const float* __restrict__ Ain, const float* __restrict__ Aq,
               const unsigned short* __restrict__ Wvh,
               const unsigned short* __restrict__ Wcath,
               const float* __restrict__ bv, const float* __restrict__ bcat,
               unsigned short* __restrict__ valueP,
               unsigned short* __restrict__ logitsB) {
    constexpr int K = 256, NK = 8;
    __shared__ unsigned short sA[2][4096];   // [64][32] fp32, swizzled units
    __shared__ unsigned short sB[2][4096];   // [128][32] bf16 linear

    const int t   = threadIdx.x;
    const int blk = blockIdx.x;
    const bool isVal = (blk < 1024);

    const float* A; const unsigned short* B; const float* bias;
    int brow, bcol;
    if (isVal) {            // XCD-paired: blk and blk+8 share brow
        const int g = blk >> 4, w = blk & 15;
        brow = (g * 8 + (w & 7)) * 64;
        bcol = ((w >> 3) & 1) * 128;
        A = Ain; B = Wvh; bias = bv;
    } else {
        brow = (blk - 1024) * 64; bcol = 0;
        A = Aq; B = Wcath; bias = bcat;
    }

    // A staging: thread t -> row t>>3 (0..31), swizzled col-quad; 2 issues
    const int srow = t >> 3;
    const int scq  = (t & 7) ^ (srow & 7);
    const float* aG = A + (size_t)(brow + srow) * K + scq * 4;
    const size_t aI = (size_t)32 * K;

    // B staging (linear): row t>>2 (0..63), col-octet (t&3)*8; 2 issues
    const unsigned short* bG = B + (size_t)(bcol + (t >> 2)) * K + (t & 3) * 8;
    const size_t bI = (size_t)64 * K;

    const int l   = t & 63;
    const int wid = t >> 6;
    const int wr  = wid >> 1, wc = wid & 1;   // wave tile: 32 rows x 64 cols
    const int fr  = l & 15,   kq = l >> 4;

    f32x4 acc[2][4] = {};

#define STAGE(buf, ks_) { const int k0_ = (ks_) * 32;                    \
       gl2lds16(aG + k0_,      &sA[buf][t * 8]);                         \
       gl2lds16(aG + k0_ + aI, &sA[buf][2048 + t * 8]);                  \
       gl2lds16(bG + k0_,      &sB[buf][t * 8]);                         \
       gl2lds16(bG + k0_ + bI, &sB[buf][2048 + t * 8]); }

    STAGE(0, 0);                     // 4 outstanding
    STAGE(1, 1);                     // 8 outstanding

    for (int ks = 0; ks < NK; ++ks) {
        const int cur = ks & 1;
        if (ks < NK - 1) asm volatile("s_waitcnt vmcnt(4)" ::: "memory");
        else             asm volatile("s_waitcnt vmcnt(0)" ::: "memory");
        __builtin_amdgcn_s_barrier();
        __builtin_amdgcn_sched_barrier(0);

        bf16x8 af[2], bf_[4];
#pragma unroll
        for (int m = 0; m < 2; ++m)
            af[m]  = cvt_frag(sA[cur], wr * 32 + m * 16 + fr, kq);
#pragma unroll
        for (int n = 0; n < 4; ++n)
            bf_[n] = *(const bf16x8*)&sB[cur][(wc * 64 + n * 16 + fr) * 32 + kq * 8];

#pragma unroll
        for (int m = 0; m < 2; ++m)
#pragma unroll
            for (int n = 0; n < 4; ++n)   // swapped operands: C[m16+fr][n16+kq4+j]
                acc[m][n] = __builtin_amdgcn_mfma_f32_16x16x32_bf16(
                    bf_[n], af[m], acc[m][n], 0, 0, 0);

        __builtin_amdgcn_sched_barrier(0);
        __builtin_amdgcn_s_barrier();
        if (ks + 2 < NK) STAGE(cur, ks + 2);
    }
#undef STAGE

    // epilogue: thread owns row (..+fr), 4 consecutive cols (..+kq*4+j)
#pragma unroll
    for (int m = 0; m < 2; ++m) {
        const int row = brow + wr * 32 + m * 16 + fr;
        size_t rbase;
        if (isVal) {
            const int nb_ = row >> 12;
            const int pix = row & 4095;
            const int y   = pix >> 6, x = pix & 63;
            rbase = ((size_t)nb_ * PPIX + (size_t)(y + 1) * PW + (x + 1)) * DM;
        } else {
            rbase = (size_t)row * LG;
        }
#pragma unroll
        for (int n = 0; n < 4; ++n) {
            const int colq = bcol + wc * 64 + n * 16 + kq * 4;
            const float4 b4 = *(const float4*)&bias[colq];
            us4 o;
            o[0] = f2bf(acc[m][n][0] + b4.x);
            o[1] = f2bf(acc[m][n][1] + b4.y);
            o[2] = f2bf(acc[m][n][2] + b4.z);
            o[3] = f2bf(acc[m][n][3] + b4.w);
            *(us4*)&(isVal ? valueP : logitsB)[rbase + colq] = o;
        }
    }
}

// ---------------------------------------------------------------------------
// out = sampledH @ Woh^T + bo (fp32 out). bf16 A and B via linear gl2lds,
// 32 KB LDS, 2-deep counted pipeline, XCD-paired row-tile mapping.
// ---------------------------------------------------------------------------
__global__ __launch_bounds__(256, 4)
void gemm_out(const unsigned short* __restrict__ A,
              const unsigned short* __restrict__ B,
              const float* __restrict__ bias, float* __restrict__ C) {
    constexpr int K = 256, N = DM, NK = 8;
    __shared__ unsigned short sA[2][4096];
    __shared__ unsigned short sB[2][4096];

    const int t   = threadIdx.x;
    const int blk = blockIdx.x;              // 0..511
    const int g = blk >> 4, w = blk & 15;    // XCD-paired mapping
    const int brow = (g * 8 + (w & 7)) * 128;
    const int bcol = ((w >> 3) & 1) * 128;

    const unsigned short* aG = A + (size_t)(brow + (t >> 2)) * K + (t & 3) * 8;
    const unsigned short* bG = B + (size_t)(bcol + (t >> 2)) * K + (t & 3) * 8;
    const size_t rs64 = (size_t)64 * K;

    const int l   = t & 63;
    const int wid = t >> 6;
    const int wr  = wid >> 1, wc = wid & 1;
    const int fr  = l & 15,   kq = l >> 4;

    f32x4 acc[4][4] = {};

#define STAGEO(buf, ks_) { const int k0_ = (ks_) * 32;                   \
       gl2lds16(aG + k0_,        &sA[buf][t * 8]);                       \
       gl2lds16(aG + k0_ + rs64, &sA[buf][2048 + t * 8]);                \
       gl2lds16(bG + k0_,        &sB[buf][t * 8]);                       \
       gl2lds16(bG + k0_ + rs64, &sB[buf][2048 + t * 8]); }

    STAGEO(0, 0);                    // 4 outstanding
    STAGEO(1, 1);                    // 8 outstanding

    for (int ks = 0; ks < NK; ++ks) {
        const int cur = ks & 1;
        if (ks < NK - 1) asm volatile("s_waitcnt vmcnt(4)" ::: "memory");
        else             asm volatile("s_waitcnt vmcnt(0)" ::: "memory");
        __builtin_amdgcn_s_barrier();
        __builtin_amdgcn_sched_barrier(0);

        bf16x8 af[4], bfr[4];
#pragma unroll
        for (int m = 0; m < 4; ++m)
            af[m]  = *(const bf16x8*)&sA[cur][(wr * 64 + m * 16 + fr) * 32 + kq * 8];
#pragma unroll
        for (int n = 0; n < 4; ++n)
            bfr[n] = *(const bf16x8*)&sB[cur][(wc * 64 + n * 16 + fr) * 32 + kq * 8];

#pragma unroll
        for (int m = 0; m < 4; ++m)
#pragma unroll
            for (int n = 0; n < 4; ++n)   // swapped: C[m16+fr][n16+kq4+j]
                acc[m][n] = __builtin_amdgcn_mfma_f32_16x16x32_bf16(
                    bfr[n], af[m], acc[m][n], 0, 0, 0);

        __builtin_amdgcn_sched_barrier(0);
        __builtin_amdgcn_s_barrier();
        if (ks + 2 < NK) STAGEO(cur, ks + 2);
    }
#undef STAGEO

#pragma unroll
    for (int m = 0; m < 4; ++m) {
        const int row = brow + wr * 64 + m * 16 + fr;
#pragma unroll
        for (int n = 0; n < 4; ++n) {
            const int colq = bcol + wc * 64 + n * 16 + kq * 4;
            const float4 bs = *(const float4*)&bias[colq];
            float4 o;
            o.x = acc[m][n][0] + bs.x; o.y = acc[m][n][1] + bs.y;
            o.z = acc[m][n][2] + bs.z; o.w = acc[m][n][3] + bs.w;
            *(float4*)&C[(size_t)row * N + colq] = o;
        }
    }
}

// ---------------------------------------------------------------------------
// Fused softmax + bilinear sampling — one wave per query.
// half = lane>>5 owns y-corner; c8 = lane&31 owns channels [c8*8,+8).
// Two 16B gathers per point per half; halves combined via shfl_xor(32).
// Branch-free via zero-padded image + clamp. XCD-swizzled (batch k -> XCD k).
// ---------------------------------------------------------------------------
__global__ __launch_bounds__(256)
void sample_kernel(const float* __restrict__ refp,
                   const unsigned short* __restrict__ valueP,
                   const unsigned short* __restrict__ logitsB,
                   unsigned short* __restrict__ sampledH) {
    const int vb   = (blockIdx.x & 7) * 1024 + (blockIdx.x >> 3);
    const int wid  = threadIdx.x >> 6;
    const int b    = vb * 4 + wid;
    const int n    = b >> 12;
    const int lane = threadIdx.x & 63;

    const int tp  = lane & 31;
    const int pm  = tp >> 2, ppt = tp & 3;
    const unsigned short* lg = logitsB + (size_t)b * LG;

    const float rx = refp[(size_t)b * 2 + 0];
    const float ry = refp[(size_t)b * 2 + 1];
    const float ox = bf2f(lg[pm * 8 + ppt * 2 + 0]);
    const float oy = bf2f(lg[pm * 8 + ppt * 2 + 1]);
    const float la = bf2f(lg[64 + tp]);

    const float x = fminf(fmaxf(fmaf(rx, (float)WW, ox) - 0.5f, -1.0f), 64.0f);
    const float y = fminf(fmaxf(fmaf(ry, (float)HH, oy) - 0.5f, -1.0f), 64.0f);

    float mx = fmaxf(la, __shfl_xor(la, 1));
    mx = fmaxf(mx, __shfl_xor(mx, 2));
    const float e = __expf(la - mx);
    float den = e + __shfl_xor(e, 1);
    den += __shfl_xor(den, 2);
    const float w = e / den;

    const int half = lane >> 5;
    const int c8   = lane & 31;
    const int mh   = c8 >> 2;
    const unsigned short* vbase = valueP + (size_t)n * (PPIX * DM) + c8 * 8;

    float accv[8] = {};
#pragma unroll
    for (int p = 0; p < PP; ++p) {
        const int   sl = mh * PP + p;
        const float xp = __shfl(x, sl);
        const float yp = __shfl(y, sl);
        const float wp = __shfl(w, sl);

        const float x0f = floorf(xp), y0f = floorf(yp);
        const int   x0 = (int)x0f,   y0 = (int)y0f;
        const float wx1 = xp - x0f,  wy1 = yp - y0f;
        const float wy  = half ? wy1 : (1.f - wy1);
        const float wA  = wp * wy * (1.f - wx1);
        const float wB  = wp * wy * wx1;

        const unsigned short* p0 =
            vbase + (size_t)((y0 + 1 + half) * PW + (x0 + 1)) * DM;
        const us8 gA = *(const us8*)(p0);
        const us8 gB = *(const us8*)(p0 + DM);
#pragma unroll
        for (int j = 0; j < 8; ++j) {
            accv[j] = fmaf(wA, bf2f(gA[j]), accv[j]);
            accv[j] = fmaf(wB, bf2f(gB[j]), accv[j]);
        }
    }

#pragma unroll
    for (int j = 0; j < 8; ++j)
        accv[j] += __shfl_xor(accv[j], 32);

    if (half == 0) {
        us8 o;
#pragma unroll
        for (int j = 0; j < 8; ++j) o[j] = f2bf(accv[j]);
        *(us8*)&sampledH[(size_t)b * DM + c8 * 8] = o;
    }
}

// ---------------------------------------------------------------------------
extern "C" void kernel_launch(void* const* d_in, const int* in_sizes, int n_in,
                              void* d_out, int out_size, void* d_ws, size_t ws_size,
                              hipStream_t stream) {
    const float* query  = (const float*)d_in[0];   // [8,4096,256]
    const float* refp   = (const float*)d_in[1];   // [8,4096,2]
    const float* inputf = (const float*)d_in[2];   // [8,4096,256]
    const float* Wv   = (const float*)d_in[5];     // [256,256]
    const float* bv   = (const float*)d_in[6];     // [256]
    const float* Woff = (const float*)d_in[7];     // [64,256]
    const float* boff = (const float*)d_in[8];     // [64]
    const float* Wa   = (const float*)d_in[9];     // [32,256]
    const float* ba   = (const float*)d_in[10];    // [32]
    const float* Wo   = (const float*)d_in[11];    // [256,256]
    const float* bo   = (const float*)d_in[12];    // [256]
    float* out = (float*)d_out;

    const int Mrows = NB * LQN;  // 32768

    // workspace layout (ushort units)
    unsigned short* sampledH = (unsigned short*)d_ws;              //  8,388,608
    unsigned short* valueP   = sampledH + (size_t)Mrows * DM;      //  9,193,472
    unsigned short* logitsB  = valueP   + (size_t)NB * PPIX * DM;  //  4,194,304
    unsigned short* Wvh      = logitsB  + (size_t)Mrows * LG;      //     65,536
    unsigned short* Woh      = Wvh      + 65536;                   //     65,536
    unsigned short* Wcath    = Woh      + 65536;                   //     32,768
    float*          bcat     = (float*)(Wcath + 32768);            //        128

    // 1. prep: weight bf16 conversion + image border zero
    prep_kernel<<<1427, 256, 0, stream>>>(Wv, Wo, Woff, Wa, boff, ba,
                                          Wvh, Woh, Wcath, bcat, valueP);

    // 2. dual GEMM (BM=64, high occupancy, counted vmcnt): value + logits
    dual_gemm<<<1536, 256, 0, stream>>>(inputf, query, Wvh, Wcath, bv, bcat,
                                        valueP, logitsB);

    // 3. softmax + bilinear sampling -> sampledH (bf16)
    sample_kernel<<<Mrows / 4, 256, 0, stream>>>(refp, valueP, logitsB, sampledH);

    // 4. out = sampled @ Wo^T + bo (fp32 out)
    gemm_out<<<512, 256, 0, stream>>>(sampledH, Woh, bo, out);
}